// Round 1
// baseline (1071.414 us; speedup 1.0000x reference)
//
#include <hip/hip_runtime.h>
#include <hip/hip_bf16.h>
#include <stdint.h>

// Problem dims (B=2, T=2048, H=1024, F=4096, E=8)
#define BT   4096
#define HDIM 1024
#define FDIM 4096
#define EDIM 8
#define TOPP 0.8f

typedef unsigned short u16;
typedef __attribute__((ext_vector_type(8))) short  short8;
typedef __attribute__((ext_vector_type(8))) unsigned short ushort8;
typedef __attribute__((ext_vector_type(4))) float  f32x4;

// ---------- helpers ----------
__device__ __forceinline__ u16 f2bf(float f) {
  uint32_t u = __builtin_bit_cast(uint32_t, f);
  uint32_t r = u + 0x7FFFu + ((u >> 16) & 1u);   // RNE
  return (u16)(r >> 16);
}

__device__ __forceinline__ void gload_lds16(const void* g, void* l) {
  __builtin_amdgcn_global_load_lds(
      (const __attribute__((address_space(1))) uint32_t*)g,
      (__attribute__((address_space(3))) uint32_t*)l, 16, 0, 0);
}

// ---------- router: probs -> top-p gate (exactly replicates stable argsort semantics) ----------
__global__ __launch_bounds__(256) void router_kernel(
    const float* __restrict__ x, const float* __restrict__ Wr,
    const float* __restrict__ br, float* __restrict__ gate) {
  const int wid  = threadIdx.x >> 6;
  const int lane = threadIdx.x & 63;
  const int token = blockIdx.x * 4 + wid;   // grid = BT/4
  const float* xr = x + (size_t)token * HDIM;

  float p[8] = {0.f,0.f,0.f,0.f,0.f,0.f,0.f,0.f};
  // lane covers 16 h-values
  #pragma unroll
  for (int j = 0; j < 16; ++j) {
    int hh = lane * 16 + j;
    float xv = xr[hh];
    const float* wrow = Wr + (size_t)hh * 8;
    #pragma unroll
    for (int e = 0; e < 8; ++e) p[e] += xv * wrow[e];
  }
  #pragma unroll
  for (int off = 32; off > 0; off >>= 1) {
    #pragma unroll
    for (int e = 0; e < 8; ++e) p[e] += __shfl_xor(p[e], off, 64);
  }
  // all lanes now hold identical full dots
  float mx = -1e30f;
  #pragma unroll
  for (int e = 0; e < 8; ++e) { p[e] += br[e]; mx = fmaxf(mx, p[e]); }
  float s = 0.f;
  #pragma unroll
  for (int e = 0; e < 8; ++e) { p[e] = expf(p[e] - mx); s += p[e]; }
  float inv = 1.0f / s;
  #pragma unroll
  for (int e = 0; e < 8; ++e) p[e] *= inv;

  if (lane == 0) {
    float g[8];
    #pragma unroll
    for (int e = 0; e < 8; ++e) {
      float pe = p[e];
      float cum = pe; int rank = 0;
      #pragma unroll
      for (int e2 = 0; e2 < 8; ++e2) {
        if (e2 == e) continue;
        // expert e2 ranked before e in argsort(-probs) (stable: ties by index)
        bool before = (p[e2] > pe) || (p[e2] == pe && e2 < e);
        if (before) { cum += p[e2]; rank++; }
      }
      bool keep = (cum < TOPP) || (rank == 0);
      g[e] = keep ? pe : 0.f;
    }
    float* gp = gate + (size_t)token * 8;
    #pragma unroll
    for (int e = 0; e < 8; ++e) gp[e] = g[e];
  }
}

// ---------- cast x f32 -> bf16 ----------
__global__ __launch_bounds__(256) void cast_x_kernel(
    const float* __restrict__ in, u16* __restrict__ out) {
  int i = (blockIdx.x * 256 + threadIdx.x) * 8;
  float4 a = *(const float4*)(in + i);
  float4 b = *(const float4*)(in + i + 4);
  ushort8 o;
  o[0] = f2bf(a.x); o[1] = f2bf(a.y); o[2] = f2bf(a.z); o[3] = f2bf(a.w);
  o[4] = f2bf(b.x); o[5] = f2bf(b.y); o[6] = f2bf(b.z); o[7] = f2bf(b.w);
  *(ushort8*)(out + i) = o;
}

// ---------- transpose + cast: per-expert (R,C) f32 -> (C,R) bf16 ----------
__global__ __launch_bounds__(256) void transpose_cast_kernel(
    const float* __restrict__ in, u16* __restrict__ out, int R, int C) {
  __shared__ float tile[32][33];
  const int e = blockIdx.z;
  const float* ip = in + (size_t)e * R * C;
  u16* op = out + (size_t)e * R * C;
  int x  = blockIdx.x * 32 + threadIdx.x;   // C coord
  int y0 = blockIdx.y * 32;                 // R tile base
  int ty = threadIdx.y;                     // 0..7
  #pragma unroll
  for (int j = 0; j < 32; j += 8)
    tile[ty + j][threadIdx.x] = ip[(size_t)(y0 + ty + j) * C + x];
  __syncthreads();
  int xo  = y0 + threadIdx.x;               // R coord (contiguous on out)
  int yo0 = blockIdx.x * 32;
  #pragma unroll
  for (int j = 0; j < 32; j += 8)
    op[(size_t)(yo0 + ty + j) * R + xo] = f2bf(tile[threadIdx.x][ty + j]);
}

// ---------- GEMM: C(MxN) = A(MxK) * Bt(NxK)^T, bf16 in, f32 acc ----------
// EPI 0: Hout = bf16(relu(acc + bias[n]))
// EPI 1: Cout = gate[m][expert] * (acc + bias[n])         (write)
// EPI 2: Cout += gate[m][expert] * (acc + bias[n])        (accumulate)
template <int Ndim, int Kdim, int EPI>
__global__ __launch_bounds__(256, 2) void gemm_kernel(
    const u16* __restrict__ A, const u16* __restrict__ Bt,
    const float* __restrict__ bias, const float* __restrict__ gate,
    int expert, u16* __restrict__ Hout, float* __restrict__ Cout) {
  __shared__ u16 Atile[128 * 32];
  __shared__ u16 Btile[128 * 32];

  const int tid  = threadIdx.x;
  const int wid  = tid >> 6;
  const int lane = tid & 63;
  const int bm = blockIdx.y, bn = blockIdx.x;
  const int wm = wid >> 1, wn = wid & 1;     // 2x2 waves, each 64x64
  const int l4  = lane >> 4;                 // 0..3
  const int l15 = lane & 15;

  f32x4 acc[4][4];
  #pragma unroll
  for (int i = 0; i < 4; ++i)
    #pragma unroll
    for (int j = 0; j < 4; ++j) acc[i][j] = {0.f, 0.f, 0.f, 0.f};

  const int srow = lane >> 2;        // 0..15 within 16-row chunk
  const int scol = (lane & 3) * 8;   // k offset (8 bf16 = 16B)
  const int rowA0 = bm * 128;
  const int rowB0 = bn * 128;

  for (int k0 = 0; k0 < Kdim; k0 += 32) {
    __syncthreads();   // all waves done reading LDS from previous iter
    #pragma unroll
    for (int i = 0; i < 2; ++i) {
      int c = wid * 2 + i;           // chunk 0..7 (16 rows each)
      const u16* ga = A  + (size_t)(rowA0 + c * 16 + srow) * Kdim + k0 + scol;
      gload_lds16(ga, &Atile[c * 512]);
      const u16* gb = Bt + (size_t)(rowB0 + c * 16 + srow) * Kdim + k0 + scol;
      gload_lds16(gb, &Btile[c * 512]);
    }
    __syncthreads();   // implies vmcnt(0): staged data visible

    short8 af[4], bf[4];
    #pragma unroll
    for (int mi = 0; mi < 4; ++mi)
      af[mi] = *(const short8*)&Atile[(wm * 64 + mi * 16 + l15) * 32 + l4 * 8];
    #pragma unroll
    for (int ni = 0; ni < 4; ++ni)
      bf[ni] = *(const short8*)&Btile[(wn * 64 + ni * 16 + l15) * 32 + l4 * 8];
    #pragma unroll
    for (int mi = 0; mi < 4; ++mi)
      #pragma unroll
      for (int ni = 0; ni < 4; ++ni)
        acc[mi][ni] = __builtin_amdgcn_mfma_f32_16x16x32_bf16(
            af[mi], bf[ni], acc[mi][ni], 0, 0, 0);
  }

  // epilogue
  const int cm0 = bm * 128 + wm * 64;
  const int cn0 = bn * 128 + wn * 64;
  float bv[4];
  #pragma unroll
  for (int ni = 0; ni < 4; ++ni) bv[ni] = bias[cn0 + ni * 16 + l15];

  #pragma unroll
  for (int mi = 0; mi < 4; ++mi) {
    #pragma unroll
    for (int r = 0; r < 4; ++r) {
      const int row = cm0 + mi * 16 + l4 * 4 + r;
      float gv = 0.f;
      if (EPI != 0) gv = gate[(size_t)row * 8 + expert];
      #pragma unroll
      for (int ni = 0; ni < 4; ++ni) {
        const int col = cn0 + ni * 16 + l15;
        float v = acc[mi][ni][r] + bv[ni];
        if (EPI == 0) {
          v = fmaxf(v, 0.f);
          Hout[(size_t)row * Ndim + col] = f2bf(v);
        } else if (EPI == 1) {
          Cout[(size_t)row * Ndim + col] = gv * v;
        } else {
          Cout[(size_t)row * Ndim + col] += gv * v;
        }
      }
    }
  }
}

// ---------- launch ----------
extern "C" void kernel_launch(void* const* d_in, const int* in_sizes, int n_in,
                              void* d_out, int out_size, void* d_ws, size_t ws_size,
                              hipStream_t stream) {
  const float* x  = (const float*)d_in[0];
  const float* Wr = (const float*)d_in[1];
  const float* br = (const float*)d_in[2];
  const float* W1 = (const float*)d_in[3];
  const float* b1 = (const float*)d_in[4];
  const float* W2 = (const float*)d_in[5];
  const float* b2 = (const float*)d_in[6];
  float* out = (float*)d_out;

  // workspace layout (~176 MB)
  char* p = (char*)d_ws;
  float* gate = (float*)p; p += (size_t)BT * EDIM * 4;
  u16* xb   = (u16*)p;     p += (size_t)BT * HDIM * 2;
  u16* w1t  = (u16*)p;     p += (size_t)EDIM * FDIM * HDIM * 2;   // (E,F,H)
  u16* w2t  = (u16*)p;     p += (size_t)EDIM * HDIM * FDIM * 2;   // (E,H,F)
  u16* h    = (u16*)p;     p += (size_t)BT * FDIM * 2;            // (BT,F) one expert

  router_kernel<<<BT / 4, 256, 0, stream>>>(x, Wr, br, gate);
  cast_x_kernel<<<(BT * HDIM) / (256 * 8), 256, 0, stream>>>(x, xb);
  // W1 (E,H,F) -> W1T (E,F,H)
  transpose_cast_kernel<<<dim3(FDIM / 32, HDIM / 32, EDIM), dim3(32, 8), 0, stream>>>(
      W1, w1t, HDIM, FDIM);
  // W2 (E,F,H) -> W2T (E,H,F)
  transpose_cast_kernel<<<dim3(HDIM / 32, FDIM / 32, EDIM), dim3(32, 8), 0, stream>>>(
      W2, w2t, FDIM, HDIM);

  for (int e = 0; e < EDIM; ++e) {
    // h = relu(x @ W1_e + b1_e)   (M=BT, N=F, K=H)
    gemm_kernel<FDIM, HDIM, 0><<<dim3(FDIM / 128, BT / 128), 256, 0, stream>>>(
        xb, w1t + (size_t)e * FDIM * HDIM, b1 + (size_t)e * FDIM,
        nullptr, 0, h, nullptr);
    // out (+)= gate_e * (h @ W2_e + b2_e)   (M=BT, N=H, K=F)
    if (e == 0) {
      gemm_kernel<HDIM, FDIM, 1><<<dim3(HDIM / 128, BT / 128), 256, 0, stream>>>(
          h, w2t + (size_t)e * HDIM * FDIM, b2 + (size_t)e * HDIM,
          gate, e, nullptr, out);
    } else {
      gemm_kernel<HDIM, FDIM, 2><<<dim3(HDIM / 128, BT / 128), 256, 0, stream>>>(
          h, w2t + (size_t)e * HDIM * FDIM, b2 + (size_t)e * HDIM,
          gate, e, nullptr, out);
    }
  }
}